// Round 3
// baseline (524.734 us; speedup 1.0000x reference)
//
#include <hip/hip_runtime.h>

// WaveNet inference. Exploits: (1) only last timestep feeds the FC head,
// (2) skip is overwritten each layer (only layer 15's skip used),
// (3) receptive field at t=T-1 is only 77 steps.
// Inputs float32, tokens int32. Round 3: 1024 threads/block (4 waves/SIMD
// for latency hiding; round-2 ran 1 wave/SIMD -> 21 cyc/FMA).

#define BB 16
#define TT 8192
#define LL 16
#define W0 77   // receptive-field window of x0
#define NT 1024

__device__ __forceinline__ float fast_sigmoid(float x) {
  return 1.f / (1.f + __expf(-x));
}
__device__ __forceinline__ float fast_tanh(float x) {
  return 2.f / (1.f + __expf(-2.f * x)) - 1.f;
}

__global__ __launch_bounds__(NT) void wavenet_kernel(
    const int* __restrict__ tokens,
    const float* __restrict__ emb,
    const float* __restrict__ init_w, const float* __restrict__ init_b,
    const float* __restrict__ dil_w,  const float* __restrict__ dil_b,
    const float* __restrict__ filt_w, const float* __restrict__ filt_b,
    const float* __restrict__ gate_w, const float* __restrict__ gate_b,
    const float* __restrict__ res_w,  const float* __restrict__ res_b,
    const float* __restrict__ skip_w, const float* __restrict__ skip_b,
    const float* __restrict__ end1_w, const float* __restrict__ end1_b,
    const float* __restrict__ end2_w, const float* __restrict__ end2_b,
    const float* __restrict__ fc1_w,  const float* __restrict__ fc1_b,
    const float* __restrict__ fc2_w,  const float* __restrict__ fc2_b,
    const float* __restrict__ fc3_w,  const float* __restrict__ fc3_b,
    const float* __restrict__ fc4_w,  const float* __restrict__ fc4_b,
    float* __restrict__ out)
{
  __shared__ float xbuf[W0 * 32];        // [u][c], u=0 is t=T-1
  __shared__ float resbuf[(W0 - 1) * 32];
  __shared__ float xmid[(W0 - 2) * 32];
  __shared__ float wts[7 * 1024];        // transposed layer weights (also init_w^T: 3200)
  __shared__ float bias[4 * 32];
  __shared__ int   tok[W0];
  __shared__ float vecA[256], vecB[256];

  const int b = blockIdx.x;
  const int tid = threadIdx.x;

  // ---- stage 0: tokens + init_w^T into LDS ----
  if (tid < W0) tok[tid] = tokens[b * TT + (TT - 1 - tid)];
  for (int idx = tid; idx < 100 * 32; idx += NT) {
    int e = idx >> 5, c = idx & 31;
    wts[idx] = init_w[c * 100 + e];   // iwT[e][c]
  }
  if (tid < 32) bias[tid] = init_b[tid];
  __syncthreads();

  // x0[u][c] = init_b[c] + sum_e init_w[c][e] * emb[tok[u]][e]
  for (int idx = tid; idx < W0 * 32; idx += NT) {
    int u = idx >> 5, c = idx & 31;
    const float* er = emb + tok[u] * 100;
    float acc = bias[c];
    #pragma unroll 4
    for (int e = 0; e < 100; e++) acc += wts[e * 32 + c] * er[e];
    xbuf[idx] = acc;
  }
  __syncthreads();

  // ---- 16 layers over shrinking window ----
  int Win = W0;
  for (int i = 0; i < LL; i++) {
    const int d = 1 << (i & 3);
    const int Wout = Win - d - 1;

    // stage weights transposed: [rc][c] layout (1024 elems = one shot)
    {
      int rc = tid >> 5, c = tid & 31;
      int base = (i * 32 + c) * 32 + rc;
      wts[tid]        = dil_w[base * 2 + 0];
      wts[1024 + tid] = dil_w[base * 2 + 1];
      wts[2048 + tid] = filt_w[base * 2 + 0];
      wts[3072 + tid] = filt_w[base * 2 + 1];
      wts[4096 + tid] = gate_w[base * 2 + 0];
      wts[5120 + tid] = gate_w[base * 2 + 1];
      wts[6144 + tid] = res_w[base];
    }
    if (tid < 32) {
      bias[tid]      = dil_b[i * 32 + tid];
      bias[32 + tid] = filt_b[i * 32 + tid];
      bias[64 + tid] = gate_b[i * 32 + tid];
      bias[96 + tid] = res_b[i * 32 + tid];
    }
    __syncthreads();

    // residual[vr][c] = db[c] + D0@x[vr+d] + D1@x[vr], vr in [0, Wout]
    for (int idx = tid; idx < (Wout + 1) * 32; idx += NT) {
      int vr = idx >> 5, c = idx & 31;
      float acc = bias[c];
      const float* xa = xbuf + (vr + d) * 32;
      const float* xz = xbuf + vr * 32;
      #pragma unroll
      for (int rc = 0; rc < 32; rc++)
        acc += wts[rc * 32 + c] * xa[rc] + wts[1024 + rc * 32 + c] * xz[rc];
      resbuf[idx] = acc;
    }
    __syncthreads();

    // f/g at uf in [0, Wout-1]: F0@res[uf+1] + F1@res[uf]
    for (int idx = tid; idx < Wout * 32; idx += NT) {
      int uf = idx >> 5, c = idx & 31;
      float af = bias[32 + c], ag = bias[64 + c];
      const float* r1 = resbuf + (uf + 1) * 32;  // residual[t]
      const float* r0 = resbuf + uf * 32;        // residual[t+1]
      #pragma unroll
      for (int rc = 0; rc < 32; rc++) {
        float a = r1[rc], z = r0[rc];
        af += wts[2048 + rc * 32 + c] * a + wts[3072 + rc * 32 + c] * z;
        ag += wts[4096 + rc * 32 + c] * a + wts[5120 + rc * 32 + c] * z;
      }
      xmid[idx] = fast_tanh(af) * fast_sigmoid(ag);
    }
    __syncthreads();

    // xnext[uf][c] = rb[c] + R@xmid[uf] + residual[uf+1]
    for (int idx = tid; idx < Wout * 32; idx += NT) {
      int uf = idx >> 5, c = idx & 31;
      float acc = bias[96 + c] + resbuf[(uf + 1) * 32 + c];
      const float* xm = xmid + uf * 32;
      #pragma unroll
      for (int rc = 0; rc < 32; rc++)
        acc += wts[6144 + rc * 32 + c] * xm[rc];
      xbuf[idx] = acc;
    }
    __syncthreads();
    Win = Wout;
  }

  // ---- tail: only layer 15's skip at t=T-1 matters; xmid[0..31] holds it ----
  if (tid < 256) {
    float acc = skip_b[15 * 256 + tid];
    const float* wr = skip_w + (15 * 256 + tid) * 32;
    #pragma unroll
    for (int c = 0; c < 32; c++) acc += wr[c] * xmid[c];
    vecA[tid] = fmaxf(acc, 0.f);
  }
  __syncthreads();
  if (tid < 256) {
    float acc = end1_b[tid];
    const float* wr = end1_w + tid * 256;
    for (int k = 0; k < 256; k++) acc += wr[k] * vecA[k];
    vecB[tid] = fmaxf(acc, 0.f);
  }
  __syncthreads();
  if (tid < 256) {
    float acc = end2_b[tid];
    const float* wr = end2_w + tid * 256;
    for (int k = 0; k < 256; k++) acc += wr[k] * vecB[k];
    vecA[tid] = acc;
  }
  __syncthreads();
  if (tid < 128) {
    float acc = fc1_b[tid];
    const float* wr = fc1_w + tid * 256;
    for (int k = 0; k < 256; k++) acc += wr[k] * vecA[k];
    vecB[tid] = fmaxf(acc, 0.f);
  }
  __syncthreads();
  if (tid < 128) {
    float acc = fc2_b[tid];
    const float* wr = fc2_w + tid * 128;
    for (int k = 0; k < 128; k++) acc += wr[k] * vecB[k];
    vecA[tid] = fmaxf(acc, 0.f);
  }
  __syncthreads();
  if (tid < 64) {
    float acc = fc3_b[tid];
    const float* wr = fc3_w + tid * 128;
    for (int k = 0; k < 128; k++) acc += wr[k] * vecA[k];
    vecB[tid] = fmaxf(acc, 0.f);
  }
  __syncthreads();
  if (tid < 256) {
    float acc = fc4_b[tid];
    const float* wr = fc4_w + tid * 64;
    #pragma unroll
    for (int k = 0; k < 64; k++) acc += wr[k] * vecB[k];
    out[b * 256 + tid] = acc;
  }
}

extern "C" void kernel_launch(void* const* d_in, const int* in_sizes, int n_in,
                              void* d_out, int out_size, void* d_ws, size_t ws_size,
                              hipStream_t stream) {
  wavenet_kernel<<<BB, NT, 0, stream>>>(
      (const int*)d_in[0],    (const float*)d_in[1],  (const float*)d_in[2],  (const float*)d_in[3],
      (const float*)d_in[4],  (const float*)d_in[5],  (const float*)d_in[6],  (const float*)d_in[7],
      (const float*)d_in[8],  (const float*)d_in[9],  (const float*)d_in[10], (const float*)d_in[11],
      (const float*)d_in[12], (const float*)d_in[13], (const float*)d_in[14], (const float*)d_in[15],
      (const float*)d_in[16], (const float*)d_in[17], (const float*)d_in[18], (const float*)d_in[19],
      (const float*)d_in[20], (const float*)d_in[21], (const float*)d_in[22], (const float*)d_in[23],
      (const float*)d_in[24], (const float*)d_in[25], (float*)d_out);
}

// Round 4
// 474.249 us; speedup vs baseline: 1.1065x; 1.1065x over previous
//
#include <hip/hip_runtime.h>

// WaveNet inference. Exploits: (1) only last timestep feeds the FC head,
// (2) skip is overwritten each layer (only layer 15's skip used),
// (3) receptive field at t=T-1 is only 77 steps.
// Inputs float32, tokens int32.
// Round 4: NT=512 (2 waves/SIMD; round-3's NT=1024 forced 64-VGPR cap ->
// 9 MB scratch spills). Weight prefetch into regs hides staging latency.

#define BB 16
#define TT 8192
#define LL 16
#define W0 77   // receptive-field window of x0
#define NT 512

__device__ __forceinline__ float fast_sigmoid(float x) {
  return 1.f / (1.f + __expf(-x));
}
__device__ __forceinline__ float fast_tanh(float x) {
  return 2.f / (1.f + __expf(-2.f * x)) - 1.f;
}

__global__ __launch_bounds__(NT) void wavenet_kernel(
    const int* __restrict__ tokens,
    const float* __restrict__ emb,
    const float* __restrict__ init_w, const float* __restrict__ init_b,
    const float* __restrict__ dil_w,  const float* __restrict__ dil_b,
    const float* __restrict__ filt_w, const float* __restrict__ filt_b,
    const float* __restrict__ gate_w, const float* __restrict__ gate_b,
    const float* __restrict__ res_w,  const float* __restrict__ res_b,
    const float* __restrict__ skip_w, const float* __restrict__ skip_b,
    const float* __restrict__ end1_w, const float* __restrict__ end1_b,
    const float* __restrict__ end2_w, const float* __restrict__ end2_b,
    const float* __restrict__ fc1_w,  const float* __restrict__ fc1_b,
    const float* __restrict__ fc2_w,  const float* __restrict__ fc2_b,
    const float* __restrict__ fc3_w,  const float* __restrict__ fc3_b,
    const float* __restrict__ fc4_w,  const float* __restrict__ fc4_b,
    float* __restrict__ out)
{
  __shared__ float xbuf[W0 * 32];        // [u][c], u=0 is t=T-1
  __shared__ float resbuf[(W0 - 1) * 32];
  __shared__ float xmid[(W0 - 2) * 32];
  __shared__ float wts[7 * 1024];        // transposed layer weights (also init_w^T: 3200)
  __shared__ float bias[4 * 32];
  __shared__ int   tok[W0];
  __shared__ float vecA[256], vecB[256];

  const int b = blockIdx.x;
  const int tid = threadIdx.x;

  // per-thread weight-prefetch registers (layer i+1 loaded during layer i)
  float pw[7][2];
  float pb[4];

  // ---- stage 0: tokens + init_w^T into LDS ----
  if (tid < W0) tok[tid] = tokens[b * TT + (TT - 1 - tid)];
  for (int idx = tid; idx < 100 * 32; idx += NT) {
    int e = idx >> 5, c = idx & 31;
    wts[idx] = init_w[c * 100 + e];   // iwT[e][c]
  }
  if (tid < 32) bias[tid] = init_b[tid];

  // prefetch layer-0 weights into regs (consumed at top of layer loop)
  {
    const int i = 0;
    #pragma unroll
    for (int j = 0; j < 2; j++) {
      int idx = tid + j * NT;
      int rc = idx >> 5, c = idx & 31;
      int base = (i * 32 + c) * 32 + rc;
      pw[0][j] = dil_w[base * 2 + 0];
      pw[1][j] = dil_w[base * 2 + 1];
      pw[2][j] = filt_w[base * 2 + 0];
      pw[3][j] = filt_w[base * 2 + 1];
      pw[4][j] = gate_w[base * 2 + 0];
      pw[5][j] = gate_w[base * 2 + 1];
      pw[6][j] = res_w[base];
    }
    if (tid < 32) {
      pb[0] = dil_b[tid]; pb[1] = filt_b[tid];
      pb[2] = gate_b[tid]; pb[3] = res_b[tid];
    }
  }
  __syncthreads();

  // x0[u][c] = init_b[c] + sum_e init_w[c][e] * emb[tok[u]][e]
  for (int idx = tid; idx < W0 * 32; idx += NT) {
    int u = idx >> 5, c = idx & 31;
    const float* er = emb + tok[u] * 100;
    float acc = bias[c];
    #pragma unroll 4
    for (int e = 0; e < 100; e++) acc += wts[e * 32 + c] * er[e];
    xbuf[idx] = acc;
  }
  __syncthreads();

  // ---- 16 layers over shrinking window ----
  int Win = W0;
  for (int i = 0; i < LL; i++) {
    const int d = 1 << (i & 3);
    const int Wout = Win - d - 1;

    // commit prefetched weights (layer i) from regs into LDS
    #pragma unroll
    for (int j = 0; j < 2; j++) {
      int idx = tid + j * NT;
      wts[idx]        = pw[0][j];
      wts[1024 + idx] = pw[1][j];
      wts[2048 + idx] = pw[2][j];
      wts[3072 + idx] = pw[3][j];
      wts[4096 + idx] = pw[4][j];
      wts[5120 + idx] = pw[5][j];
      wts[6144 + idx] = pw[6][j];
    }
    if (tid < 32) {
      bias[tid]      = pb[0];
      bias[32 + tid] = pb[1];
      bias[64 + tid] = pb[2];
      bias[96 + tid] = pb[3];
    }
    __syncthreads();

    // issue prefetch of layer i+1 (latency hidden under the 3 phases below)
    if (i + 1 < LL) {
      const int ii = i + 1;
      #pragma unroll
      for (int j = 0; j < 2; j++) {
        int idx = tid + j * NT;
        int rc = idx >> 5, c = idx & 31;
        int base = (ii * 32 + c) * 32 + rc;
        pw[0][j] = dil_w[base * 2 + 0];
        pw[1][j] = dil_w[base * 2 + 1];
        pw[2][j] = filt_w[base * 2 + 0];
        pw[3][j] = filt_w[base * 2 + 1];
        pw[4][j] = gate_w[base * 2 + 0];
        pw[5][j] = gate_w[base * 2 + 1];
        pw[6][j] = res_w[base];
      }
      if (tid < 32) {
        pb[0] = dil_b[ii * 32 + tid]; pb[1] = filt_b[ii * 32 + tid];
        pb[2] = gate_b[ii * 32 + tid]; pb[3] = res_b[ii * 32 + tid];
      }
    }

    // phase1: residual[vr][c] = db[c] + D0@x[vr+d] + D1@x[vr], vr in [0, Wout]
    for (int idx = tid; idx < (Wout + 1) * 32; idx += NT) {
      int vr = idx >> 5, c = idx & 31;
      float acc = bias[c];
      const float* xa = xbuf + (vr + d) * 32;
      const float* xz = xbuf + vr * 32;
      #pragma unroll
      for (int rc = 0; rc < 32; rc++)
        acc += wts[rc * 32 + c] * xa[rc] + wts[1024 + rc * 32 + c] * xz[rc];
      resbuf[idx] = acc;
    }
    __syncthreads();

    // phase2: f/g at uf in [0, Wout-1]: F0@res[uf+1] + F1@res[uf]
    for (int idx = tid; idx < Wout * 32; idx += NT) {
      int uf = idx >> 5, c = idx & 31;
      float af = bias[32 + c], ag = bias[64 + c];
      const float* r1 = resbuf + (uf + 1) * 32;  // residual[t]
      const float* r0 = resbuf + uf * 32;        // residual[t+1]
      #pragma unroll
      for (int rc = 0; rc < 32; rc++) {
        float a = r1[rc], z = r0[rc];
        af += wts[2048 + rc * 32 + c] * a + wts[3072 + rc * 32 + c] * z;
        ag += wts[4096 + rc * 32 + c] * a + wts[5120 + rc * 32 + c] * z;
      }
      xmid[idx] = fast_tanh(af) * fast_sigmoid(ag);
    }
    __syncthreads();

    // phase3: xnext[uf][c] = rb[c] + R@xmid[uf] + residual[uf+1]
    for (int idx = tid; idx < Wout * 32; idx += NT) {
      int uf = idx >> 5, c = idx & 31;
      float acc = bias[96 + c] + resbuf[(uf + 1) * 32 + c];
      const float* xm = xmid + uf * 32;
      #pragma unroll
      for (int rc = 0; rc < 32; rc++)
        acc += wts[6144 + rc * 32 + c] * xm[rc];
      xbuf[idx] = acc;
    }
    __syncthreads();
    Win = Wout;
  }

  // ---- tail: only layer 15's skip at t=T-1 matters; xmid[0..31] holds it ----
  if (tid < 256) {
    float acc = skip_b[15 * 256 + tid];
    const float* wr = skip_w + (15 * 256 + tid) * 32;
    #pragma unroll
    for (int c = 0; c < 32; c++) acc += wr[c] * xmid[c];
    vecA[tid] = fmaxf(acc, 0.f);
  }
  __syncthreads();
  if (tid < 256) {
    float acc = end1_b[tid];
    const float* wr = end1_w + tid * 256;
    for (int k = 0; k < 256; k++) acc += wr[k] * vecA[k];
    vecB[tid] = fmaxf(acc, 0.f);
  }
  __syncthreads();
  if (tid < 256) {
    float acc = end2_b[tid];
    const float* wr = end2_w + tid * 256;
    for (int k = 0; k < 256; k++) acc += wr[k] * vecB[k];
    vecA[tid] = acc;
  }
  __syncthreads();
  if (tid < 128) {
    float acc = fc1_b[tid];
    const float* wr = fc1_w + tid * 256;
    for (int k = 0; k < 256; k++) acc += wr[k] * vecA[k];
    vecB[tid] = fmaxf(acc, 0.f);
  }
  __syncthreads();
  if (tid < 128) {
    float acc = fc2_b[tid];
    const float* wr = fc2_w + tid * 128;
    for (int k = 0; k < 128; k++) acc += wr[k] * vecB[k];
    vecA[tid] = fmaxf(acc, 0.f);
  }
  __syncthreads();
  if (tid < 64) {
    float acc = fc3_b[tid];
    const float* wr = fc3_w + tid * 128;
    for (int k = 0; k < 128; k++) acc += wr[k] * vecA[k];
    vecB[tid] = fmaxf(acc, 0.f);
  }
  __syncthreads();
  if (tid < 256) {
    float acc = fc4_b[tid];
    const float* wr = fc4_w + tid * 64;
    #pragma unroll
    for (int k = 0; k < 64; k++) acc += wr[k] * vecB[k];
    out[b * 256 + tid] = acc;
  }
}

extern "C" void kernel_launch(void* const* d_in, const int* in_sizes, int n_in,
                              void* d_out, int out_size, void* d_ws, size_t ws_size,
                              hipStream_t stream) {
  wavenet_kernel<<<BB, NT, 0, stream>>>(
      (const int*)d_in[0],    (const float*)d_in[1],  (const float*)d_in[2],  (const float*)d_in[3],
      (const float*)d_in[4],  (const float*)d_in[5],  (const float*)d_in[6],  (const float*)d_in[7],
      (const float*)d_in[8],  (const float*)d_in[9],  (const float*)d_in[10], (const float*)d_in[11],
      (const float*)d_in[12], (const float*)d_in[13], (const float*)d_in[14], (const float*)d_in[15],
      (const float*)d_in[16], (const float*)d_in[17], (const float*)d_in[18], (const float*)d_in[19],
      (const float*)d_in[20], (const float*)d_in[21], (const float*)d_in[22], (const float*)d_in[23],
      (const float*)d_in[24], (const float*)d_in[25], (float*)d_out);
}

// Round 5
// 348.068 us; speedup vs baseline: 1.5076x; 1.3625x over previous
//
#include <hip/hip_runtime.h>

// WaveNet inference. Exploits: (1) only last timestep feeds the FC head,
// (2) skip is overwritten each layer (only layer 15's skip used),
// (3) receptive field at t=T-1 is only 77 steps.
// Inputs float32, tokens int32.
// Round 5: NT=256 (proven no-spill; NT>=512 always spilled). ILP instead:
// register-resident weight columns per phase, J=4 interleaved accumulators,
// float4 LDS reads, balanced-tree partial sums.

#define BB 16
#define TT 8192
#define LL 16
#define W0 77   // receptive-field window of x0
#define NT 256

__device__ __forceinline__ float fast_sigmoid(float x) {
  return 1.f / (1.f + __expf(-x));
}
__device__ __forceinline__ float fast_tanh(float x) {
  return 2.f / (1.f + __expf(-2.f * x)) - 1.f;
}

__global__ __launch_bounds__(NT) void wavenet_kernel(
    const int* __restrict__ tokens,
    const float* __restrict__ emb,
    const float* __restrict__ init_w, const float* __restrict__ init_b,
    const float* __restrict__ dil_w,  const float* __restrict__ dil_b,
    const float* __restrict__ filt_w, const float* __restrict__ filt_b,
    const float* __restrict__ gate_w, const float* __restrict__ gate_b,
    const float* __restrict__ res_w,  const float* __restrict__ res_b,
    const float* __restrict__ skip_w, const float* __restrict__ skip_b,
    const float* __restrict__ end1_w, const float* __restrict__ end1_b,
    const float* __restrict__ end2_w, const float* __restrict__ end2_b,
    const float* __restrict__ fc1_w,  const float* __restrict__ fc1_b,
    const float* __restrict__ fc2_w,  const float* __restrict__ fc2_b,
    const float* __restrict__ fc3_w,  const float* __restrict__ fc3_b,
    const float* __restrict__ fc4_w,  const float* __restrict__ fc4_b,
    float* __restrict__ out)
{
  __shared__ float xbuf[W0 * 32];        // [u][c], u=0 is t=T-1
  __shared__ float resbuf[(W0 - 1) * 32];
  __shared__ float xmid[(W0 - 2) * 32];
  __shared__ float wts[7 * 1024];        // transposed layer weights (also init_w^T: 3200)
  __shared__ float bias[4 * 32];
  __shared__ int   tok[W0];
  __shared__ float vecA[256], vecB[256];

  const int b = blockIdx.x;
  const int tid = threadIdx.x;
  const int c = tid & 31;   // channel owned by this thread
  const int g = tid >> 5;   // output-row group 0..7

  // per-thread weight-prefetch registers (layer i+1 loaded during layer i)
  float pw[7][4];
  float pb[4];

  // ---- stage 0: tokens + init_w^T into LDS ----
  if (tid < W0) tok[tid] = tokens[b * TT + (TT - 1 - tid)];
  for (int idx = tid; idx < 100 * 32; idx += NT) {
    int e = idx >> 5, cc = idx & 31;
    wts[idx] = init_w[cc * 100 + e];   // iwT[e][c]
  }
  if (tid < 32) bias[tid] = init_b[tid];

  // prefetch layer-0 weights into regs
  #pragma unroll
  for (int j = 0; j < 4; j++) {
    int idx = tid + j * NT;
    int rc = idx >> 5, cc = idx & 31;
    int base = cc * 32 + rc;
    pw[0][j] = dil_w[base * 2 + 0];
    pw[1][j] = dil_w[base * 2 + 1];
    pw[2][j] = filt_w[base * 2 + 0];
    pw[3][j] = filt_w[base * 2 + 1];
    pw[4][j] = gate_w[base * 2 + 0];
    pw[5][j] = gate_w[base * 2 + 1];
    pw[6][j] = res_w[base];
  }
  if (tid < 32) {
    pb[0] = dil_b[tid]; pb[1] = filt_b[tid];
    pb[2] = gate_b[tid]; pb[3] = res_b[tid];
  }
  __syncthreads();

  // ---- init conv: x0[u][c] = init_b[c] + sum_e iwT[e][c]*emb[tok[u]][e] ----
  {
    const float bc = bias[c];
    for (int base0 = 0; base0 < W0; base0 += 32) {
      float acc[4] = {bc, bc, bc, bc};
      const float* er[4];
      #pragma unroll
      for (int j = 0; j < 4; j++) {
        int u = base0 + g + 8 * j; if (u > W0 - 1) u = W0 - 1;  // clamp: OOB token would fault
        er[j] = emb + tok[u] * 100;
      }
      #pragma unroll 5
      for (int eq = 0; eq < 100; eq += 4) {
        float w0 = wts[(eq+0)*32+c], w1 = wts[(eq+1)*32+c];
        float w2 = wts[(eq+2)*32+c], w3 = wts[(eq+3)*32+c];
        #pragma unroll
        for (int j = 0; j < 4; j++) {
          float4 e4 = *(const float4*)(er[j] + eq);
          float t0 = w0 * e4.x + w1 * e4.y;
          float t1 = w2 * e4.z + w3 * e4.w;
          acc[j] += t0 + t1;
        }
      }
      #pragma unroll
      for (int j = 0; j < 4; j++) {
        int u = base0 + g + 8 * j;
        if (u < W0) xbuf[u * 32 + c] = acc[j];
      }
    }
  }
  __syncthreads();

  // ---- 16 layers over shrinking window ----
  int Win = W0;
  for (int i = 0; i < LL; i++) {
    const int d = 1 << (i & 3);
    const int Wout = Win - d - 1;

    // commit prefetched weights (layer i) from regs into LDS, [rc][c] layout
    #pragma unroll
    for (int j = 0; j < 4; j++) {
      int idx = tid + j * NT;
      wts[idx]        = pw[0][j];
      wts[1024 + idx] = pw[1][j];
      wts[2048 + idx] = pw[2][j];
      wts[3072 + idx] = pw[3][j];
      wts[4096 + idx] = pw[4][j];
      wts[5120 + idx] = pw[5][j];
      wts[6144 + idx] = pw[6][j];
    }
    if (tid < 32) {
      bias[tid]      = pb[0];
      bias[32 + tid] = pb[1];
      bias[64 + tid] = pb[2];
      bias[96 + tid] = pb[3];
    }
    __syncthreads();

    // issue prefetch of layer i+1 (latency hidden under the 3 phases below)
    if (i + 1 < LL) {
      const int ii = i + 1;
      #pragma unroll
      for (int j = 0; j < 4; j++) {
        int idx = tid + j * NT;
        int rc = idx >> 5, cc = idx & 31;
        int base = (ii * 32 + cc) * 32 + rc;
        pw[0][j] = dil_w[base * 2 + 0];
        pw[1][j] = dil_w[base * 2 + 1];
        pw[2][j] = filt_w[base * 2 + 0];
        pw[3][j] = filt_w[base * 2 + 1];
        pw[4][j] = gate_w[base * 2 + 0];
        pw[5][j] = gate_w[base * 2 + 1];
        pw[6][j] = res_w[base];
      }
      if (tid < 32) {
        pb[0] = dil_b[ii * 32 + tid]; pb[1] = filt_b[ii * 32 + tid];
        pb[2] = gate_b[ii * 32 + tid]; pb[3] = res_b[ii * 32 + tid];
      }
    }

    // phase1: residual[vr][c] = db[c] + D0@x[vr+d] + D1@x[vr], vr in [0,Wout]
    {
      float wd0[32], wd1[32];
      #pragma unroll
      for (int rc = 0; rc < 32; rc++) {
        wd0[rc] = wts[rc * 32 + c];
        wd1[rc] = wts[1024 + rc * 32 + c];
      }
      const float bd = bias[c];
      const int n1 = Wout + 1;
      for (int base0 = 0; base0 < n1; base0 += 32) {
        float acc[4] = {bd, bd, bd, bd};
        #pragma unroll
        for (int rcq = 0; rcq < 32; rcq += 4) {
          #pragma unroll
          for (int j = 0; j < 4; j++) {
            int vr = base0 + g + 8 * j;
            float4 xa = *(const float4*)&xbuf[(vr + d) * 32 + rcq];
            float4 xz = *(const float4*)&xbuf[vr * 32 + rcq];
            float t0 = wd0[rcq+0] * xa.x + wd0[rcq+1] * xa.y;
            float t1 = wd0[rcq+2] * xa.z + wd0[rcq+3] * xa.w;
            float t2 = wd1[rcq+0] * xz.x + wd1[rcq+1] * xz.y;
            float t3 = wd1[rcq+2] * xz.z + wd1[rcq+3] * xz.w;
            acc[j] += (t0 + t1) + (t2 + t3);
          }
        }
        #pragma unroll
        for (int j = 0; j < 4; j++) {
          int vr = base0 + g + 8 * j;
          if (vr < n1) resbuf[vr * 32 + c] = acc[j];
        }
      }
    }
    __syncthreads();

    // phase2: f/g at uf in [0,Wout-1]: F0@res[uf+1]+F1@res[uf]; same for G
    {
      float wf0[32], wf1[32], wg0[32], wg1[32];
      #pragma unroll
      for (int rc = 0; rc < 32; rc++) {
        wf0[rc] = wts[2048 + rc * 32 + c];
        wf1[rc] = wts[3072 + rc * 32 + c];
        wg0[rc] = wts[4096 + rc * 32 + c];
        wg1[rc] = wts[5120 + rc * 32 + c];
      }
      const float bf = bias[32 + c], bg = bias[64 + c];
      for (int base0 = 0; base0 < Wout; base0 += 32) {
        float af[4] = {bf, bf, bf, bf};
        float ag[4] = {bg, bg, bg, bg};
        #pragma unroll
        for (int rcq = 0; rcq < 32; rcq += 4) {
          #pragma unroll
          for (int j = 0; j < 4; j++) {
            int uf = base0 + g + 8 * j;
            float4 r1 = *(const float4*)&resbuf[(uf + 1) * 32 + rcq];
            float4 r0 = *(const float4*)&resbuf[uf * 32 + rcq];
            float f0 = wf0[rcq+0] * r1.x + wf0[rcq+1] * r1.y;
            float f1 = wf0[rcq+2] * r1.z + wf0[rcq+3] * r1.w;
            float f2 = wf1[rcq+0] * r0.x + wf1[rcq+1] * r0.y;
            float f3 = wf1[rcq+2] * r0.z + wf1[rcq+3] * r0.w;
            af[j] += (f0 + f1) + (f2 + f3);
            float g0 = wg0[rcq+0] * r1.x + wg0[rcq+1] * r1.y;
            float g1 = wg0[rcq+2] * r1.z + wg0[rcq+3] * r1.w;
            float g2 = wg1[rcq+0] * r0.x + wg1[rcq+1] * r0.y;
            float g3 = wg1[rcq+2] * r0.z + wg1[rcq+3] * r0.w;
            ag[j] += (g0 + g1) + (g2 + g3);
          }
        }
        #pragma unroll
        for (int j = 0; j < 4; j++) {
          int uf = base0 + g + 8 * j;
          if (uf < Wout) xmid[uf * 32 + c] = fast_tanh(af[j]) * fast_sigmoid(ag[j]);
        }
      }
    }
    __syncthreads();

    // phase3: xnext[uf][c] = rb[c] + R@xmid[uf] + residual[uf+1]
    {
      float wrr[32];
      #pragma unroll
      for (int rc = 0; rc < 32; rc++) wrr[rc] = wts[6144 + rc * 32 + c];
      const float br = bias[96 + c];
      for (int base0 = 0; base0 < Wout; base0 += 32) {
        float acc[4];
        #pragma unroll
        for (int j = 0; j < 4; j++) {
          int uf = base0 + g + 8 * j;
          acc[j] = br + resbuf[(uf + 1) * 32 + c];
        }
        #pragma unroll
        for (int rcq = 0; rcq < 32; rcq += 4) {
          #pragma unroll
          for (int j = 0; j < 4; j++) {
            int uf = base0 + g + 8 * j;
            float4 xm = *(const float4*)&xmid[uf * 32 + rcq];
            float t0 = wrr[rcq+0] * xm.x + wrr[rcq+1] * xm.y;
            float t1 = wrr[rcq+2] * xm.z + wrr[rcq+3] * xm.w;
            acc[j] += t0 + t1;
          }
        }
        #pragma unroll
        for (int j = 0; j < 4; j++) {
          int uf = base0 + g + 8 * j;
          if (uf < Wout) xbuf[uf * 32 + c] = acc[j];
        }
      }
    }
    __syncthreads();
    Win = Wout;
  }

  // ---- tail: only layer 15's skip at t=T-1 matters; xmid[0..31] holds it ----
  {
    float acc = skip_b[15 * 256 + tid];
    const float* wr = skip_w + (15 * 256 + tid) * 32;
    #pragma unroll
    for (int k = 0; k < 32; k += 4) {
      float4 w = *(const float4*)&wr[k];
      acc += (w.x * xmid[k] + w.y * xmid[k+1]) + (w.z * xmid[k+2] + w.w * xmid[k+3]);
    }
    vecA[tid] = fmaxf(acc, 0.f);
  }
  __syncthreads();
  {
    const float* wr = end1_w + tid * 256;
    float a4[4] = {0.f, 0.f, 0.f, 0.f};
    #pragma unroll 4
    for (int k = 0; k < 256; k += 16) {
      #pragma unroll
      for (int q = 0; q < 4; q++) {
        float4 w = *(const float4*)&wr[k + 4 * q];
        a4[q] += (w.x * vecA[k+4*q] + w.y * vecA[k+4*q+1]) + (w.z * vecA[k+4*q+2] + w.w * vecA[k+4*q+3]);
      }
    }
    vecB[tid] = fmaxf(end1_b[tid] + (a4[0] + a4[1]) + (a4[2] + a4[3]), 0.f);
  }
  __syncthreads();
  {
    const float* wr = end2_w + tid * 256;
    float a4[4] = {0.f, 0.f, 0.f, 0.f};
    #pragma unroll 4
    for (int k = 0; k < 256; k += 16) {
      #pragma unroll
      for (int q = 0; q < 4; q++) {
        float4 w = *(const float4*)&wr[k + 4 * q];
        a4[q] += (w.x * vecB[k+4*q] + w.y * vecB[k+4*q+1]) + (w.z * vecB[k+4*q+2] + w.w * vecB[k+4*q+3]);
      }
    }
    vecA[tid] = end2_b[tid] + (a4[0] + a4[1]) + (a4[2] + a4[3]);
  }
  __syncthreads();
  if (tid < 128) {
    const float* wr = fc1_w + tid * 256;
    float a4[4] = {0.f, 0.f, 0.f, 0.f};
    #pragma unroll 4
    for (int k = 0; k < 256; k += 16) {
      #pragma unroll
      for (int q = 0; q < 4; q++) {
        float4 w = *(const float4*)&wr[k + 4 * q];
        a4[q] += (w.x * vecA[k+4*q] + w.y * vecA[k+4*q+1]) + (w.z * vecA[k+4*q+2] + w.w * vecA[k+4*q+3]);
      }
    }
    vecB[tid] = fmaxf(fc1_b[tid] + (a4[0] + a4[1]) + (a4[2] + a4[3]), 0.f);
  }
  __syncthreads();
  if (tid < 128) {
    const float* wr = fc2_w + tid * 128;
    float a4[4] = {0.f, 0.f, 0.f, 0.f};
    #pragma unroll 2
    for (int k = 0; k < 128; k += 16) {
      #pragma unroll
      for (int q = 0; q < 4; q++) {
        float4 w = *(const float4*)&wr[k + 4 * q];
        a4[q] += (w.x * vecB[k+4*q] + w.y * vecB[k+4*q+1]) + (w.z * vecB[k+4*q+2] + w.w * vecB[k+4*q+3]);
      }
    }
    vecA[tid] = fmaxf(fc2_b[tid] + (a4[0] + a4[1]) + (a4[2] + a4[3]), 0.f);
  }
  __syncthreads();
  if (tid < 64) {
    const float* wr = fc3_w + tid * 128;
    float a4[4] = {0.f, 0.f, 0.f, 0.f};
    #pragma unroll 2
    for (int k = 0; k < 128; k += 16) {
      #pragma unroll
      for (int q = 0; q < 4; q++) {
        float4 w = *(const float4*)&wr[k + 4 * q];
        a4[q] += (w.x * vecA[k+4*q] + w.y * vecA[k+4*q+1]) + (w.z * vecA[k+4*q+2] + w.w * vecA[k+4*q+3]);
      }
    }
    vecB[tid] = fmaxf(fc3_b[tid] + (a4[0] + a4[1]) + (a4[2] + a4[3]), 0.f);
  }
  __syncthreads();
  {
    const float* wr = fc4_w + tid * 64;
    float a4[4] = {0.f, 0.f, 0.f, 0.f};
    #pragma unroll
    for (int k = 0; k < 64; k += 16) {
      #pragma unroll
      for (int q = 0; q < 4; q++) {
        float4 w = *(const float4*)&wr[k + 4 * q];
        a4[q] += (w.x * vecB[k+4*q] + w.y * vecB[k+4*q+1]) + (w.z * vecB[k+4*q+2] + w.w * vecB[k+4*q+3]);
      }
    }
    out[b * 256 + tid] = fc4_b[tid] + (a4[0] + a4[1]) + (a4[2] + a4[3]);
  }
}

extern "C" void kernel_launch(void* const* d_in, const int* in_sizes, int n_in,
                              void* d_out, int out_size, void* d_ws, size_t ws_size,
                              hipStream_t stream) {
  wavenet_kernel<<<BB, NT, 0, stream>>>(
      (const int*)d_in[0],    (const float*)d_in[1],  (const float*)d_in[2],  (const float*)d_in[3],
      (const float*)d_in[4],  (const float*)d_in[5],  (const float*)d_in[6],  (const float*)d_in[7],
      (const float*)d_in[8],  (const float*)d_in[9],  (const float*)d_in[10], (const float*)d_in[11],
      (const float*)d_in[12], (const float*)d_in[13], (const float*)d_in[14], (const float*)d_in[15],
      (const float*)d_in[16], (const float*)d_in[17], (const float*)d_in[18], (const float*)d_in[19],
      (const float*)d_in[20], (const float*)d_in[21], (const float*)d_in[22], (const float*)d_in[23],
      (const float*)d_in[24], (const float*)d_in[25], (float*)d_out);
}

// Round 6
// 239.993 us; speedup vs baseline: 2.1865x; 1.4503x over previous
//
#include <hip/hip_runtime.h>

// WaveNet inference on MFMA. Exploits: (1) only last timestep feeds the FC
// head, (2) skip overwritten each layer (only layer 15's matters),
// (3) receptive field at t=T-1 is 77 steps.
// Round 6: the 32ch x 32ch convs are v_mfma_f32_32x32x16_bf16 per 32-row
// tile (1 wave/tile). x/res/xmid kept as bf16 LDS copies for A-fragments;
// residual carry path stays f32 (C-operand preload). 3 barriers/layer.

#define BB 16
#define TT 8192
#define LL 16
#define W0 77
#define NT 256

typedef __attribute__((ext_vector_type(8)))  short short8;
typedef __attribute__((ext_vector_type(16))) float float16;

#define MFMA_B16(a, b, c) __builtin_amdgcn_mfma_f32_32x32x16_bf16(a, b, c, 0, 0, 0)

__device__ __forceinline__ short f2bs(float f) {   // f32 -> bf16 bits, RNE
  union { float ff; unsigned u; } v; v.ff = f;
  unsigned u = v.u;
  return (short)((u + 0x7FFFu + ((u >> 16) & 1u)) >> 16);
}
__device__ __forceinline__ float b2f(short h) {
  union { unsigned u; float f; } v;
  v.u = ((unsigned)(unsigned short)h) << 16; return v.f;
}
__device__ __forceinline__ float fast_sigmoid(float x) {
  return 1.f / (1.f + __expf(-x));
}
__device__ __forceinline__ float fast_tanh(float x) {
  return 2.f / (1.f + __expf(-2.f * x)) - 1.f;
}

// B-fragments (two K=16 halves) from staged wts [rc][c] f32 layout.
// B[k][n]: n = lane&31, k = (lane>>5)*8 + j  (per-instruction k-local).
__device__ __forceinline__ void bfrag2(const float* w, int n, int kh, short8* out) {
  #pragma unroll
  for (int h = 0; h < 2; h++) {
    short8 v;
    #pragma unroll
    for (int j = 0; j < 8; j++) v[j] = f2bs(w[(16 * h + kh * 8 + j) * 32 + n]);
    out[h] = v;
  }
}
// A-fragments: A[m][k], m = lane&31, k-local = (lane>>5)*8 + j; row is the
// timestep. One b128 per K-half from a bf16 [row][32] LDS array.
__device__ __forceinline__ void afrag2(const short* src, int row, int kh, short8* out) {
  #pragma unroll
  for (int h = 0; h < 2; h++)
    out[h] = *(const short8*)&src[row * 32 + 16 * h + 8 * kh];
}

__global__ __launch_bounds__(NT) void wavenet_kernel(
    const int* __restrict__ tokens,
    const float* __restrict__ emb,
    const float* __restrict__ init_w, const float* __restrict__ init_b,
    const float* __restrict__ dil_w,  const float* __restrict__ dil_b,
    const float* __restrict__ filt_w, const float* __restrict__ filt_b,
    const float* __restrict__ gate_w, const float* __restrict__ gate_b,
    const float* __restrict__ res_w,  const float* __restrict__ res_b,
    const float* __restrict__ skip_w, const float* __restrict__ skip_b,
    const float* __restrict__ end1_w, const float* __restrict__ end1_b,
    const float* __restrict__ end2_w, const float* __restrict__ end2_b,
    const float* __restrict__ fc1_w,  const float* __restrict__ fc1_b,
    const float* __restrict__ fc2_w,  const float* __restrict__ fc2_b,
    const float* __restrict__ fc3_w,  const float* __restrict__ fc3_b,
    const float* __restrict__ fc4_w,  const float* __restrict__ fc4_b,
    float* __restrict__ out)
{
  __shared__ float wts[7 * 1024];      // staged layer weights, [rc][c] (init: iwT)
  __shared__ float bias[4 * 32];
  __shared__ float resbuf[76 * 32];    // f32 residual (carry path)
  __shared__ __align__(16) short xbuf_bf[W0 * 32];   // bf16 x (matmul A input)
  __shared__ __align__(16) short resbuf_bf[76 * 32]; // bf16 residual copy
  __shared__ __align__(16) short xmid_bf[76 * 32];   // bf16 f*g
  __shared__ int   tok[W0];
  __shared__ float vecA[256], vecB[256];

  const int b   = blockIdx.x;
  const int tid = threadIdx.x;
  const int lane = tid & 63;
  const int wv   = tid >> 6;        // wave id 0..3
  const int m    = lane & 31;       // A row / D col index
  const int kh   = lane >> 5;       // k-half selector
  const int g    = tid >> 5;        // init-conv row group 0..7

  float pw[7][4];                   // next-layer weight prefetch
  float pb[4];

  // ---- stage 0: tokens + init_w^T ----
  if (tid < W0) tok[tid] = tokens[b * TT + (TT - 1 - tid)];
  for (int idx = tid; idx < 100 * 32; idx += NT) {
    int e = idx >> 5, cc = idx & 31;
    wts[idx] = init_w[cc * 100 + e];   // iwT[e][c]
  }
  if (tid < 32) bias[tid] = init_b[tid];

  // prefetch layer-0 weights
  #pragma unroll
  for (int j = 0; j < 4; j++) {
    int idx = tid + j * NT;
    int rc = idx >> 5, cc = idx & 31;
    int base = cc * 32 + rc;
    pw[0][j] = dil_w[base * 2 + 0];
    pw[1][j] = dil_w[base * 2 + 1];
    pw[2][j] = filt_w[base * 2 + 0];
    pw[3][j] = filt_w[base * 2 + 1];
    pw[4][j] = gate_w[base * 2 + 0];
    pw[5][j] = gate_w[base * 2 + 1];
    pw[6][j] = res_w[base];
  }
  if (tid < 32) {
    pb[0] = dil_b[tid]; pb[1] = filt_b[tid];
    pb[2] = gate_b[tid]; pb[3] = res_b[tid];
  }
  __syncthreads();

  // ---- init conv (VALU f32, store bf16) ----
  {
    const int c = tid & 31;
    const float bc = bias[c];
    for (int base0 = 0; base0 < W0; base0 += 32) {
      float acc[4] = {bc, bc, bc, bc};
      const float* er[4];
      #pragma unroll
      for (int j = 0; j < 4; j++) {
        int u = base0 + g + 8 * j; if (u > W0 - 1) u = W0 - 1;
        er[j] = emb + tok[u] * 100;
      }
      #pragma unroll 5
      for (int eq = 0; eq < 100; eq += 4) {
        float w0 = wts[(eq+0)*32+c], w1 = wts[(eq+1)*32+c];
        float w2 = wts[(eq+2)*32+c], w3 = wts[(eq+3)*32+c];
        #pragma unroll
        for (int j = 0; j < 4; j++) {
          float4 e4 = *(const float4*)(er[j] + eq);
          acc[j] += (w0 * e4.x + w1 * e4.y) + (w2 * e4.z + w3 * e4.w);
        }
      }
      #pragma unroll
      for (int j = 0; j < 4; j++) {
        int u = base0 + g + 8 * j;
        if (u < W0) xbuf_bf[u * 32 + c] = f2bs(acc[j]);
      }
    }
  }
  __syncthreads();

  // ---- 16 layers ----
  int Win = W0;
  for (int i = 0; i < LL; i++) {
    const int d = 1 << (i & 3);
    const int Wout = Win - d - 1;
    const int T1 = (Wout + 1 + 31) >> 5;   // tiles for resbuf rows [0..Wout]
    const int T2 = (Wout + 31) >> 5;       // tiles for xmid/xnext rows [0..Wout)

    // commit prefetched weights into wts [rc][c]
    #pragma unroll
    for (int j = 0; j < 4; j++) {
      int idx = tid + j * NT;
      wts[idx]        = pw[0][j];
      wts[1024 + idx] = pw[1][j];
      wts[2048 + idx] = pw[2][j];
      wts[3072 + idx] = pw[3][j];
      wts[4096 + idx] = pw[4][j];
      wts[5120 + idx] = pw[5][j];
      wts[6144 + idx] = pw[6][j];
    }
    if (tid < 32) {
      bias[tid]      = pb[0];
      bias[32 + tid] = pb[1];
      bias[64 + tid] = pb[2];
      bias[96 + tid] = pb[3];
    }
    __syncthreads();

    // prefetch layer i+1
    if (i + 1 < LL) {
      const int ii = i + 1;
      #pragma unroll
      for (int j = 0; j < 4; j++) {
        int idx = tid + j * NT;
        int rc = idx >> 5, cc = idx & 31;
        int base = (ii * 32 + cc) * 32 + rc;
        pw[0][j] = dil_w[base * 2 + 0];
        pw[1][j] = dil_w[base * 2 + 1];
        pw[2][j] = filt_w[base * 2 + 0];
        pw[3][j] = filt_w[base * 2 + 1];
        pw[4][j] = gate_w[base * 2 + 0];
        pw[5][j] = gate_w[base * 2 + 1];
        pw[6][j] = res_w[base];
      }
      if (tid < 32) {
        pb[0] = dil_b[ii * 32 + tid]; pb[1] = filt_b[ii * 32 + tid];
        pb[2] = gate_b[ii * 32 + tid]; pb[3] = res_b[ii * 32 + tid];
      }
    }

    // ---- phase1 (MFMA): residual[vr] = db + D0@x[vr+d] + D1@x[vr] ----
    if (wv < T1) {
      const int R = wv * 32;
      short8 bD0[2], bD1[2];
      bfrag2(wts,        m, kh, bD0);
      bfrag2(wts + 1024, m, kh, bD1);
      int vra = R + m + d; if (vra > Win - 1) vra = Win - 1;
      int vrz = R + m;     if (vrz > Win - 1) vrz = Win - 1;
      short8 aA[2], aZ[2];
      afrag2(xbuf_bf, vra, kh, aA);
      afrag2(xbuf_bf, vrz, kh, aZ);
      float16 acc;
      const float bc = bias[m];
      #pragma unroll
      for (int r = 0; r < 16; r++) acc[r] = bc;
      acc = MFMA_B16(aA[0], bD0[0], acc);
      acc = MFMA_B16(aA[1], bD0[1], acc);
      acc = MFMA_B16(aZ[0], bD1[0], acc);
      acc = MFMA_B16(aZ[1], bD1[1], acc);
      #pragma unroll
      for (int r = 0; r < 16; r++) {
        int row = (r & 3) + 8 * (r >> 2) + 4 * kh;
        int vr = R + row;
        if (vr <= Wout) {
          resbuf[vr * 32 + m]    = acc[r];
          resbuf_bf[vr * 32 + m] = f2bs(acc[r]);
        }
      }
    }
    __syncthreads();

    // ---- phase2+3 (MFMA, same wave & tile, no inter-phase barrier) ----
    if (wv < T2) {
      const int R = wv * 32;
      // phase2: f/g
      short8 bF0[2], bF1[2], bG0[2], bG1[2];
      bfrag2(wts + 2048, m, kh, bF0);
      bfrag2(wts + 3072, m, kh, bF1);
      bfrag2(wts + 4096, m, kh, bG0);
      bfrag2(wts + 5120, m, kh, bG1);
      int r1 = R + m + 1; if (r1 > Wout) r1 = Wout;
      int r0 = R + m;     if (r0 > Wout) r0 = Wout;
      short8 a1[2], a0[2];
      afrag2(resbuf_bf, r1, kh, a1);
      afrag2(resbuf_bf, r0, kh, a0);
      float16 accF, accG;
      const float bf = bias[32 + m], bg = bias[64 + m];
      #pragma unroll
      for (int r = 0; r < 16; r++) { accF[r] = bf; accG[r] = bg; }
      accF = MFMA_B16(a1[0], bF0[0], accF);
      accF = MFMA_B16(a1[1], bF0[1], accF);
      accF = MFMA_B16(a0[0], bF1[0], accF);
      accF = MFMA_B16(a0[1], bF1[1], accF);
      accG = MFMA_B16(a1[0], bG0[0], accG);
      accG = MFMA_B16(a1[1], bG0[1], accG);
      accG = MFMA_B16(a0[0], bG1[0], accG);
      accG = MFMA_B16(a0[1], bG1[1], accG);
      #pragma unroll
      for (int r = 0; r < 16; r++) {
        int row = (r & 3) + 8 * (r >> 2) + 4 * kh;
        int uf = R + row;
        if (uf < Wout)
          xmid_bf[uf * 32 + m] = f2bs(fast_tanh(accF[r]) * fast_sigmoid(accG[r]));
      }
      // wave-local LDS visibility (own tile rows only)
      asm volatile("s_waitcnt lgkmcnt(0)" ::: "memory");

      // phase3: xnext = rb + R@xmid + residual[uf+1] (f32 carry in C)
      short8 bR[2];
      bfrag2(wts + 6144, m, kh, bR);
      int rx = R + m; if (rx > Wout - 1) rx = Wout - 1;
      short8 aX[2];
      afrag2(xmid_bf, rx, kh, aX);
      float16 accX;
      const float br = bias[96 + m];
      #pragma unroll
      for (int r = 0; r < 16; r++) {
        int row = (r & 3) + 8 * (r >> 2) + 4 * kh;
        int rr = R + row + 1; if (rr > Wout) rr = Wout;
        accX[r] = br + resbuf[rr * 32 + m];
      }
      accX = MFMA_B16(aX[0], bR[0], accX);
      accX = MFMA_B16(aX[1], bR[1], accX);
      #pragma unroll
      for (int r = 0; r < 16; r++) {
        int row = (r & 3) + 8 * (r >> 2) + 4 * kh;
        int uf = R + row;
        if (uf < Wout) xbuf_bf[uf * 32 + m] = f2bs(accX[r]);
      }
    }
    __syncthreads();
    Win = Wout;
  }

  // ---- tail (f32 VALU): skip(l15) -> end1 -> end2 -> fc1..fc4 ----
  {
    float acc = skip_b[15 * 256 + tid];
    const float* wr = skip_w + (15 * 256 + tid) * 32;
    #pragma unroll
    for (int k = 0; k < 32; k += 4) {
      float4 w = *(const float4*)&wr[k];
      acc += (w.x * b2f(xmid_bf[k])   + w.y * b2f(xmid_bf[k+1]))
           + (w.z * b2f(xmid_bf[k+2]) + w.w * b2f(xmid_bf[k+3]));
    }
    vecA[tid] = fmaxf(acc, 0.f);
  }
  __syncthreads();
  {
    const float* wr = end1_w + tid * 256;
    float a4[4] = {0.f, 0.f, 0.f, 0.f};
    #pragma unroll 4
    for (int k = 0; k < 256; k += 16) {
      #pragma unroll
      for (int q = 0; q < 4; q++) {
        float4 w = *(const float4*)&wr[k + 4 * q];
        a4[q] += (w.x * vecA[k+4*q] + w.y * vecA[k+4*q+1]) + (w.z * vecA[k+4*q+2] + w.w * vecA[k+4*q+3]);
      }
    }
    vecB[tid] = fmaxf(end1_b[tid] + (a4[0] + a4[1]) + (a4[2] + a4[3]), 0.f);
  }
  __syncthreads();
  {
    const float* wr = end2_w + tid * 256;
    float a4[4] = {0.f, 0.f, 0.f, 0.f};
    #pragma unroll 4
    for (int k = 0; k < 256; k += 16) {
      #pragma unroll
      for (int q = 0; q < 4; q++) {
        float4 w = *(const float4*)&wr[k + 4 * q];
        a4[q] += (w.x * vecB[k+4*q] + w.y * vecB[k+4*q+1]) + (w.z * vecB[k+4*q+2] + w.w * vecB[k+4*q+3]);
      }
    }
    vecA[tid] = end2_b[tid] + (a4[0] + a4[1]) + (a4[2] + a4[3]);
  }
  __syncthreads();
  if (tid < 128) {
    const float* wr = fc1_w + tid * 256;
    float a4[4] = {0.f, 0.f, 0.f, 0.f};
    #pragma unroll 4
    for (int k = 0; k < 256; k += 16) {
      #pragma unroll
      for (int q = 0; q < 4; q++) {
        float4 w = *(const float4*)&wr[k + 4 * q];
        a4[q] += (w.x * vecA[k+4*q] + w.y * vecA[k+4*q+1]) + (w.z * vecA[k+4*q+2] + w.w * vecA[k+4*q+3]);
      }
    }
    vecB[tid] = fmaxf(fc1_b[tid] + (a4[0] + a4[1]) + (a4[2] + a4[3]), 0.f);
  }
  __syncthreads();
  if (tid < 128) {
    const float* wr = fc2_w + tid * 128;
    float a4[4] = {0.f, 0.f, 0.f, 0.f};
    #pragma unroll 2
    for (int k = 0; k < 128; k += 16) {
      #pragma unroll
      for (int q = 0; q < 4; q++) {
        float4 w = *(const float4*)&wr[k + 4 * q];
        a4[q] += (w.x * vecB[k+4*q] + w.y * vecB[k+4*q+1]) + (w.z * vecB[k+4*q+2] + w.w * vecB[k+4*q+3]);
      }
    }
    vecA[tid] = fmaxf(fc2_b[tid] + (a4[0] + a4[1]) + (a4[2] + a4[3]), 0.f);
  }
  __syncthreads();
  if (tid < 64) {
    const float* wr = fc3_w + tid * 128;
    float a4[4] = {0.f, 0.f, 0.f, 0.f};
    #pragma unroll 2
    for (int k = 0; k < 128; k += 16) {
      #pragma unroll
      for (int q = 0; q < 4; q++) {
        float4 w = *(const float4*)&wr[k + 4 * q];
        a4[q] += (w.x * vecA[k+4*q] + w.y * vecA[k+4*q+1]) + (w.z * vecA[k+4*q+2] + w.w * vecA[k+4*q+3]);
      }
    }
    vecB[tid] = fmaxf(fc3_b[tid] + (a4[0] + a4[1]) + (a4[2] + a4[3]), 0.f);
  }
  __syncthreads();
  {
    const float* wr = fc4_w + tid * 64;
    float a4[4] = {0.f, 0.f, 0.f, 0.f};
    #pragma unroll
    for (int k = 0; k < 64; k += 16) {
      #pragma unroll
      for (int q = 0; q < 4; q++) {
        float4 w = *(const float4*)&wr[k + 4 * q];
        a4[q] += (w.x * vecB[k+4*q] + w.y * vecB[k+4*q+1]) + (w.z * vecB[k+4*q+2] + w.w * vecB[k+4*q+3]);
      }
    }
    out[b * 256 + tid] = fc4_b[tid] + (a4[0] + a4[1]) + (a4[2] + a4[3]);
  }
}

extern "C" void kernel_launch(void* const* d_in, const int* in_sizes, int n_in,
                              void* d_out, int out_size, void* d_ws, size_t ws_size,
                              hipStream_t stream) {
  wavenet_kernel<<<BB, NT, 0, stream>>>(
      (const int*)d_in[0],    (const float*)d_in[1],  (const float*)d_in[2],  (const float*)d_in[3],
      (const float*)d_in[4],  (const float*)d_in[5],  (const float*)d_in[6],  (const float*)d_in[7],
      (const float*)d_in[8],  (const float*)d_in[9],  (const float*)d_in[10], (const float*)d_in[11],
      (const float*)d_in[12], (const float*)d_in[13], (const float*)d_in[14], (const float*)d_in[15],
      (const float*)d_in[16], (const float*)d_in[17], (const float*)d_in[18], (const float*)d_in[19],
      (const float*)d_in[20], (const float*)d_in[21], (const float*)d_in[22], (const float*)d_in[23],
      (const float*)d_in[24], (const float*)d_in[25], (float*)d_out);
}

// Round 7
// 216.712 us; speedup vs baseline: 2.4213x; 1.1074x over previous
//
#include <hip/hip_runtime.h>

// WaveNet inference on MFMA. Exploits: (1) only last timestep feeds the FC
// head, (2) skip overwritten each layer (only layer 15's matters),
// (3) receptive field at t=T-1 is 77 steps.
// Round 7: weights staged in LDS as PRE-CONVERTED bf16 fragments (one
// ds_read_b128 per B-frag half, conflict-free) with double buffering
// (2 barriers/layer, commit off the critical barrier). Round 6's verified
// 32x32x16 MFMA layouts kept identical.

#define BB 16
#define TT 8192
#define LL 16
#define W0 77
#define NT 256

typedef __attribute__((ext_vector_type(8)))  short short8;
typedef __attribute__((ext_vector_type(16))) float float16;

#define MFMA_B16(a, b, c) __builtin_amdgcn_mfma_f32_32x32x16_bf16(a, b, c, 0, 0, 0)

__device__ __forceinline__ short f2bs(float f) {   // f32 -> bf16 bits, RNE
  union { float ff; unsigned u; } v; v.ff = f;
  unsigned u = v.u;
  return (short)((u + 0x7FFFu + ((u >> 16) & 1u)) >> 16);
}
__device__ __forceinline__ float b2f(short h) {
  union { unsigned u; float f; } v;
  v.u = ((unsigned)(unsigned short)h) << 16; return v.f;
}
__device__ __forceinline__ float fast_sigmoid(float x) {
  return 1.f / (1.f + __expf(-x));
}
__device__ __forceinline__ float fast_tanh(float x) {
  return 2.f / (1.f + __expf(-2.f * x)) - 1.f;
}

// A-fragment halves: A[m][k], m=lane&31, k-local=(lane>>5)*8+j; k-global=16h+8kh+j.
__device__ __forceinline__ void afrag2(const short* src, int row, int kh, short8* out) {
  #pragma unroll
  for (int h = 0; h < 2; h++)
    out[h] = *(const short8*)&src[row * 32 + 16 * h + 8 * kh];
}
// B-fragment halves from bf16 fragment-ordered LDS: one b128 each.
__device__ __forceinline__ void bfragL(const short* bw, int mat, int n, int kh, short8* out) {
  #pragma unroll
  for (int h = 0; h < 2; h++)
    out[h] = *(const short8*)&bw[((mat * 2 + h) * 64 + n * 2 + kh) * 8];
}

__global__ __launch_bounds__(NT) void wavenet_kernel(
    const int* __restrict__ tokens,
    const float* __restrict__ emb,
    const float* __restrict__ init_w, const float* __restrict__ init_b,
    const float* __restrict__ dil_w,  const float* __restrict__ dil_b,
    const float* __restrict__ filt_w, const float* __restrict__ filt_b,
    const float* __restrict__ gate_w, const float* __restrict__ gate_b,
    const float* __restrict__ res_w,  const float* __restrict__ res_b,
    const float* __restrict__ skip_w, const float* __restrict__ skip_b,
    const float* __restrict__ end1_w, const float* __restrict__ end1_b,
    const float* __restrict__ end2_w, const float* __restrict__ end2_b,
    const float* __restrict__ fc1_w,  const float* __restrict__ fc1_b,
    const float* __restrict__ fc2_w,  const float* __restrict__ fc2_b,
    const float* __restrict__ fc3_w,  const float* __restrict__ fc3_b,
    const float* __restrict__ fc4_w,  const float* __restrict__ fc4_b,
    float* __restrict__ out)
{
  // bf16 weight fragments, double buffered: [buf][ (mat*2+h)*64 + n*2+kh ][8]
  __shared__ __align__(16) short bfw[2][7168];
  __shared__ float bias2[2][128];
  __shared__ float resbuf[76 * 32];                  // f32 residual carry
  __shared__ __align__(16) short xbuf_bf[W0 * 32];
  __shared__ __align__(16) short resbuf_bf[76 * 32];
  __shared__ __align__(16) short xmid_bf[76 * 32];
  __shared__ int   tok[W0];
  __shared__ float vecA[256], vecB[256];

  const int b    = blockIdx.x;
  const int tid  = threadIdx.x;
  const int lane = tid & 63;
  const int wv   = tid >> 6;
  const int m    = lane & 31;     // output channel / A row base
  const int kh   = lane >> 5;     // k-half selector
  const int g    = tid >> 5;      // row group 0..7
  const int cc   = tid & 31;

  float pw[7][4];                 // prefetched layer weights W_mat[g+8q][cc]
  float pb[4];

  float* iwT = (float*)&bfw[1][0];   // init conv weights alias buf1 (dead then)

  // ---- stage 0 ----
  if (tid < W0) tok[tid] = tokens[b * TT + (TT - 1 - tid)];
  for (int idx = tid; idx < 100 * 32; idx += NT) {
    int e = idx >> 5, c2 = idx & 31;
    iwT[idx] = init_w[c2 * 100 + e];
  }
  if (tid < 32) vecA[tid] = init_b[tid];

  #pragma unroll
  for (int q = 0; q < 4; q++) {               // prefetch layer 0
    int rc = g + 8 * q;
    int base = cc * 32 + rc;
    pw[0][q] = dil_w[base * 2 + 0];
    pw[1][q] = dil_w[base * 2 + 1];
    pw[2][q] = filt_w[base * 2 + 0];
    pw[3][q] = filt_w[base * 2 + 1];
    pw[4][q] = gate_w[base * 2 + 0];
    pw[5][q] = gate_w[base * 2 + 1];
    pw[6][q] = res_w[base];
  }
  if (tid < 32) {
    pb[0] = dil_b[tid]; pb[1] = filt_b[tid];
    pb[2] = gate_b[tid]; pb[3] = res_b[tid];
  }
  __syncthreads();

  // ---- init conv (f32 VALU, bf16 store) ----
  {
    const float bc = vecA[cc];
    for (int base0 = 0; base0 < W0; base0 += 32) {
      float acc[4] = {bc, bc, bc, bc};
      const float* er[4];
      #pragma unroll
      for (int j = 0; j < 4; j++) {
        int u = base0 + g + 8 * j; if (u > W0 - 1) u = W0 - 1;
        er[j] = emb + tok[u] * 100;
      }
      #pragma unroll 5
      for (int eq = 0; eq < 100; eq += 4) {
        float w0 = iwT[(eq+0)*32+cc], w1 = iwT[(eq+1)*32+cc];
        float w2 = iwT[(eq+2)*32+cc], w3 = iwT[(eq+3)*32+cc];
        #pragma unroll
        for (int j = 0; j < 4; j++) {
          float4 e4 = *(const float4*)(er[j] + eq);
          acc[j] += (w0 * e4.x + w1 * e4.y) + (w2 * e4.z + w3 * e4.w);
        }
      }
      #pragma unroll
      for (int j = 0; j < 4; j++) {
        int u = base0 + g + 8 * j;
        if (u < W0) xbuf_bf[u * 32 + cc] = f2bs(acc[j]);
      }
    }
  }
  // commit layer 0 (buf0; init conv read buf1 — disjoint)
  #pragma unroll
  for (int mat = 0; mat < 7; mat++)
    #pragma unroll
    for (int q = 0; q < 4; q++)
      bfw[0][((mat * 2 + (q >> 1)) * 64 + cc * 2 + (q & 1)) * 8 + g] = f2bs(pw[mat][q]);
  if (tid < 32) {
    bias2[0][tid] = pb[0]; bias2[0][32+tid] = pb[1];
    bias2[0][64+tid] = pb[2]; bias2[0][96+tid] = pb[3];
  }
  __syncthreads();

  // ---- 16 layers, 2 barriers each ----
  int Win = W0;
  for (int i = 0; i < LL; i++) {
    const int d = 1 << (i & 3);
    const int Wout = Win - d - 1;
    const int T1 = (Wout + 32) >> 5;
    const int T2 = (Wout + 31) >> 5;
    const short* bw = bfw[i & 1];
    const float* bs = bias2[i & 1];

    // prefetch layer i+1 into regs (latency hidden under both phases)
    if (i + 1 < LL) {
      const int ii = i + 1;
      #pragma unroll
      for (int q = 0; q < 4; q++) {
        int rc = g + 8 * q;
        int base = (ii * 32 + cc) * 32 + rc;
        pw[0][q] = dil_w[base * 2 + 0];
        pw[1][q] = dil_w[base * 2 + 1];
        pw[2][q] = filt_w[base * 2 + 0];
        pw[3][q] = filt_w[base * 2 + 1];
        pw[4][q] = gate_w[base * 2 + 0];
        pw[5][q] = gate_w[base * 2 + 1];
        pw[6][q] = res_w[base];
      }
      if (tid < 32) {
        pb[0] = dil_b[ii * 32 + tid]; pb[1] = filt_b[ii * 32 + tid];
        pb[2] = gate_b[ii * 32 + tid]; pb[3] = res_b[ii * 32 + tid];
      }
    }

    // ---- phase1: residual[vr] = db + D0@x[vr+d] + D1@x[vr] ----
    if (wv < T1) {
      const int R = wv * 32;
      short8 bD0[2], bD1[2];
      bfragL(bw, 0, m, kh, bD0);
      bfragL(bw, 1, m, kh, bD1);
      int vra = R + m + d; if (vra > Win - 1) vra = Win - 1;
      int vrz = R + m;     if (vrz > Win - 1) vrz = Win - 1;
      short8 aA[2], aZ[2];
      afrag2(xbuf_bf, vra, kh, aA);
      afrag2(xbuf_bf, vrz, kh, aZ);
      float16 acc;
      const float bc = bs[m];
      #pragma unroll
      for (int r = 0; r < 16; r++) acc[r] = bc;
      acc = MFMA_B16(aA[0], bD0[0], acc);
      acc = MFMA_B16(aA[1], bD0[1], acc);
      acc = MFMA_B16(aZ[0], bD1[0], acc);
      acc = MFMA_B16(aZ[1], bD1[1], acc);
      #pragma unroll
      for (int r = 0; r < 16; r++) {
        int row = (r & 3) + 8 * (r >> 2) + 4 * kh;
        int vr = R + row;
        if (vr <= Wout) {
          resbuf[vr * 32 + m]    = acc[r];
          resbuf_bf[vr * 32 + m] = f2bs(acc[r]);
        }
      }
    }
    __syncthreads();

    // ---- phase2+3 (same wave & tile, wave-local LDS handoff) ----
    if (wv < T2) {
      const int R = wv * 32;
      short8 bF0[2], bF1[2], bG0[2], bG1[2];
      bfragL(bw, 2, m, kh, bF0);
      bfragL(bw, 3, m, kh, bF1);
      bfragL(bw, 4, m, kh, bG0);
      bfragL(bw, 5, m, kh, bG1);
      int r1 = R + m + 1; if (r1 > Wout) r1 = Wout;
      int r0 = R + m;     if (r0 > Wout) r0 = Wout;
      short8 a1[2], a0[2];
      afrag2(resbuf_bf, r1, kh, a1);
      afrag2(resbuf_bf, r0, kh, a0);
      float16 accF, accG;
      const float bf = bs[32 + m], bg = bs[64 + m];
      #pragma unroll
      for (int r = 0; r < 16; r++) { accF[r] = bf; accG[r] = bg; }
      accF = MFMA_B16(a1[0], bF0[0], accF);
      accF = MFMA_B16(a1[1], bF0[1], accF);
      accF = MFMA_B16(a0[0], bF1[0], accF);
      accF = MFMA_B16(a0[1], bF1[1], accF);
      accG = MFMA_B16(a1[0], bG0[0], accG);
      accG = MFMA_B16(a1[1], bG0[1], accG);
      accG = MFMA_B16(a0[0], bG1[0], accG);
      accG = MFMA_B16(a0[1], bG1[1], accG);
      #pragma unroll
      for (int r = 0; r < 16; r++) {
        int row = (r & 3) + 8 * (r >> 2) + 4 * kh;
        int uf = R + row;
        if (uf < Wout)
          xmid_bf[uf * 32 + m] = f2bs(fast_tanh(accF[r]) * fast_sigmoid(accG[r]));
      }
      asm volatile("s_waitcnt lgkmcnt(0)" ::: "memory");

      short8 bR[2];
      bfragL(bw, 6, m, kh, bR);
      int rx = R + m; if (rx > Wout - 1) rx = Wout - 1;
      short8 aX[2];
      afrag2(xmid_bf, rx, kh, aX);
      float16 accX;
      const float br = bs[96 + m];
      #pragma unroll
      for (int r = 0; r < 16; r++) {
        int row = (r & 3) + 8 * (r >> 2) + 4 * kh;
        int rr = R + row + 1; if (rr > Wout) rr = Wout;
        accX[r] = br + resbuf[rr * 32 + m];
      }
      accX = MFMA_B16(aX[0], bR[0], accX);
      accX = MFMA_B16(aX[1], bR[1], accX);
      #pragma unroll
      for (int r = 0; r < 16; r++) {
        int row = (r & 3) + 8 * (r >> 2) + 4 * kh;
        int uf = R + row;
        if (uf < Wout) xbuf_bf[uf * 32 + m] = f2bs(accX[r]);
      }
    }

    // commit layer i+1 into the other buffer (no extra barrier needed)
    if (i + 1 < LL) {
      short* bwN = bfw[(i + 1) & 1];
      #pragma unroll
      for (int mat = 0; mat < 7; mat++)
        #pragma unroll
        for (int q = 0; q < 4; q++)
          bwN[((mat * 2 + (q >> 1)) * 64 + cc * 2 + (q & 1)) * 8 + g] = f2bs(pw[mat][q]);
      if (tid < 32) {
        float* bN = bias2[(i + 1) & 1];
        bN[tid] = pb[0]; bN[32+tid] = pb[1]; bN[64+tid] = pb[2]; bN[96+tid] = pb[3];
      }
    }
    __syncthreads();
    Win = Wout;
  }

  // ---- tail (f32 VALU): skip(l15,t=T-1) -> end1 -> end2 -> fc1..fc4 ----
  {
    float acc = skip_b[15 * 256 + tid];
    const float* wr = skip_w + (15 * 256 + tid) * 32;
    #pragma unroll
    for (int k = 0; k < 32; k += 4) {
      float4 w = *(const float4*)&wr[k];
      acc += (w.x * b2f(xmid_bf[k])   + w.y * b2f(xmid_bf[k+1]))
           + (w.z * b2f(xmid_bf[k+2]) + w.w * b2f(xmid_bf[k+3]));
    }
    vecA[tid] = fmaxf(acc, 0.f);
  }
  __syncthreads();
  {
    const float* wr = end1_w + tid * 256;
    float a4[4] = {0.f, 0.f, 0.f, 0.f};
    #pragma unroll 4
    for (int k = 0; k < 256; k += 16) {
      #pragma unroll
      for (int q = 0; q < 4; q++) {
        float4 w = *(const float4*)&wr[k + 4 * q];
        a4[q] += (w.x * vecA[k+4*q] + w.y * vecA[k+4*q+1]) + (w.z * vecA[k+4*q+2] + w.w * vecA[k+4*q+3]);
      }
    }
    vecB[tid] = fmaxf(end1_b[tid] + (a4[0] + a4[1]) + (a4[2] + a4[3]), 0.f);
  }
  __syncthreads();
  {
    const float* wr = end2_w + tid * 256;
    float a4[4] = {0.f, 0.f, 0.f, 0.f};
    #pragma unroll 4
    for (int k = 0; k < 256; k += 16) {
      #pragma unroll
      for (int q = 0; q < 4; q++) {
        float4 w = *(const float4*)&wr[k + 4 * q];
        a4[q] += (w.x * vecB[k+4*q] + w.y * vecB[k+4*q+1]) + (w.z * vecB[k+4*q+2] + w.w * vecB[k+4*q+3]);
      }
    }
    vecA[tid] = end2_b[tid] + (a4[0] + a4[1]) + (a4[2] + a4[3]);
  }
  __syncthreads();
  if (tid < 128) {
    const float* wr = fc1_w + tid * 256;
    float a4[4] = {0.f, 0.f, 0.f, 0.f};
    #pragma unroll 4
    for (int k = 0; k < 256; k += 16) {
      #pragma unroll
      for (int q = 0; q < 4; q++) {
        float4 w = *(const float4*)&wr[k + 4 * q];
        a4[q] += (w.x * vecA[k+4*q] + w.y * vecA[k+4*q+1]) + (w.z * vecA[k+4*q+2] + w.w * vecA[k+4*q+3]);
      }
    }
    vecB[tid] = fmaxf(fc1_b[tid] + (a4[0] + a4[1]) + (a4[2] + a4[3]), 0.f);
  }
  __syncthreads();
  if (tid < 128) {
    const float* wr = fc2_w + tid * 128;
    float a4[4] = {0.f, 0.f, 0.f, 0.f};
    #pragma unroll 2
    for (int k = 0; k < 128; k += 16) {
      #pragma unroll
      for (int q = 0; q < 4; q++) {
        float4 w = *(const float4*)&wr[k + 4 * q];
        a4[q] += (w.x * vecB[k+4*q] + w.y * vecB[k+4*q+1]) + (w.z * vecB[k+4*q+2] + w.w * vecB[k+4*q+3]);
      }
    }
    vecA[tid] = fmaxf(fc2_b[tid] + (a4[0] + a4[1]) + (a4[2] + a4[3]), 0.f);
  }
  __syncthreads();
  if (tid < 64) {
    const float* wr = fc3_w + tid * 128;
    float a4[4] = {0.f, 0.f, 0.f, 0.f};
    #pragma unroll 2
    for (int k = 0; k < 128; k += 16) {
      #pragma unroll
      for (int q = 0; q < 4; q++) {
        float4 w = *(const float4*)&wr[k + 4 * q];
        a4[q] += (w.x * vecA[k+4*q] + w.y * vecA[k+4*q+1]) + (w.z * vecA[k+4*q+2] + w.w * vecA[k+4*q+3]);
      }
    }
    vecB[tid] = fmaxf(fc3_b[tid] + (a4[0] + a4[1]) + (a4[2] + a4[3]), 0.f);
  }
  __syncthreads();
  {
    const float* wr = fc4_w + tid * 64;
    float a4[4] = {0.f, 0.f, 0.f, 0.f};
    #pragma unroll
    for (int k = 0; k < 64; k += 16) {
      #pragma unroll
      for (int q = 0; q < 4; q++) {
        float4 w = *(const float4*)&wr[k + 4 * q];
        a4[q] += (w.x * vecB[k+4*q] + w.y * vecB[k+4*q+1]) + (w.z * vecB[k+4*q+2] + w.w * vecB[k+4*q+3]);
      }
    }
    out[b * 256 + tid] = fc4_b[tid] + (a4[0] + a4[1]) + (a4[2] + a4[3]);
  }
}

extern "C" void kernel_launch(void* const* d_in, const int* in_sizes, int n_in,
                              void* d_out, int out_size, void* d_ws, size_t ws_size,
                              hipStream_t stream) {
  wavenet_kernel<<<BB, NT, 0, stream>>>(
      (const int*)d_in[0],    (const float*)d_in[1],  (const float*)d_in[2],  (const float*)d_in[3],
      (const float*)d_in[4],  (const float*)d_in[5],  (const float*)d_in[6],  (const float*)d_in[7],
      (const float*)d_in[8],  (const float*)d_in[9],  (const float*)d_in[10], (const float*)d_in[11],
      (const float*)d_in[12], (const float*)d_in[13], (const float*)d_in[14], (const float*)d_in[15],
      (const float*)d_in[16], (const float*)d_in[17], (const float*)d_in[18], (const float*)d_in[19],
      (const float*)d_in[20], (const float*)d_in[21], (const float*)d_in[22], (const float*)d_in[23],
      (const float*)d_in[24], (const float*)d_in[25], (float*)d_out);
}